// Round 1
// baseline (1181.153 us; speedup 1.0000x reference)
//
#include <hip/hip_runtime.h>

#define N_NODES 50000
#define E_EDGES 800000
#define IN_F    128
#define OUT_F   64
#define HEADS   4
#define HF      (HEADS * OUT_F)   // 256
#define NEG_SLOPE 0.2f
#define EPS     1e-8f

// ---------------- Kernel 1: per-head projection + attention logits ----------
// One block per node. 256 threads: tid = h*64 + f. Wave w handles head w.
__global__ __launch_bounds__(256) void proj_kernel(
    const float* __restrict__ x,      // [N][IN_F]
    const float* __restrict__ W,      // [H][IN_F][OUT_F]
    const float* __restrict__ a_src,  // [H][OUT_F]
    const float* __restrict__ a_dst,  // [H][OUT_F]
    float* __restrict__ Wh,           // [N][H][OUT_F]
    float* __restrict__ esrc,         // [N][H]
    float* __restrict__ edst)         // [N][H]
{
    __shared__ float xs[IN_F];
    const int n = blockIdx.x;
    const int tid = threadIdx.x;
    if (tid < IN_F) xs[tid] = x[n * IN_F + tid];
    __syncthreads();

    const int h = tid >> 6;
    const int f = tid & 63;
    const float* Wp = W + h * (IN_F * OUT_F) + f;
    float acc = 0.f;
#pragma unroll 8
    for (int k = 0; k < IN_F; ++k) acc += xs[k] * Wp[k * OUT_F];

    Wh[n * HF + tid] = acc;

    float ps = acc * a_src[h * OUT_F + f];
    float pd = acc * a_dst[h * OUT_F + f];
#pragma unroll
    for (int off = 32; off > 0; off >>= 1) {
        ps += __shfl_down(ps, off);
        pd += __shfl_down(pd, off);
    }
    if (f == 0) {
        esrc[n * HEADS + h] = ps;
        edst[n * HEADS + h] = pd;
    }
}

// ---------------- Kernel 2: edge logits + segment max (over dst) ------------
__global__ __launch_bounds__(256) void edge_max_kernel(
    const int* __restrict__ src,
    const int* __restrict__ dst,
    const float* __restrict__ esrc,   // [N][H]
    const float* __restrict__ edst,   // [N][H]
    float* __restrict__ e_edge,       // [E][H]
    int* __restrict__ emax)           // [N][H] (float bits, init 0 == 0.0f)
{
    const int e = blockIdx.x * blockDim.x + threadIdx.x;
    if (e >= E_EDGES) return;
    const int s = src[e];
    const int d = dst[e];
    const float4 es = *(const float4*)(esrc + s * HEADS);
    const float4 ed = *(const float4*)(edst + d * HEADS);
    float ev[4] = { es.x + ed.x, es.y + ed.y, es.z + ed.z, es.w + ed.w };
    float4 outv;
    float* op = &outv.x;
#pragma unroll
    for (int h = 0; h < HEADS; ++h) {
        float v = ev[h];
        v = v > 0.f ? v : NEG_SLOPE * v;
        op[h] = v;
        if (v > 0.f) atomicMax(&emax[d * HEADS + h], __float_as_int(v));
    }
    *(float4*)(e_edge + e * HEADS) = outv;
}

// ---------------- Kernel 3: exp + segment sum -------------------------------
__global__ __launch_bounds__(256) void edge_exp_kernel(
    const int* __restrict__ dst,
    float* __restrict__ e_edge,       // in: e, out: exp_e
    const int* __restrict__ emax,     // [N][H] float bits
    float* __restrict__ exp_sum)      // [N][H], init 0
{
    const int e = blockIdx.x * blockDim.x + threadIdx.x;
    if (e >= E_EDGES) return;
    const int d = dst[e];
    float4 ev = *(float4*)(e_edge + e * HEADS);
    float* ep = &ev.x;
#pragma unroll
    for (int h = 0; h < HEADS; ++h) {
        const float m = __int_as_float(emax[d * HEADS + h]);
        const float ex = expf(ep[h] - m);
        ep[h] = ex;
        atomicAdd(&exp_sum[d * HEADS + h], ex);
    }
    *(float4*)(e_edge + e * HEADS) = ev;
}

// ---------------- Kernel 4: weighted scatter-add aggregation ----------------
// One wave (64 lanes) per edge; lane = f; loop over heads.
__global__ __launch_bounds__(256) void aggregate_kernel(
    const int* __restrict__ src,
    const int* __restrict__ dst,
    const float* __restrict__ e_edge,   // exp_e [E][H]
    const float* __restrict__ exp_sum,  // [N][H]
    const float* __restrict__ Wh,       // [N][H][OUT_F]
    float* __restrict__ out)            // [N][H][OUT_F], init 0
{
    const int gid = blockIdx.x * blockDim.x + threadIdx.x;
    const int e = gid >> 6;
    const int lane = threadIdx.x & 63;
    if (e >= E_EDGES) return;
    const int s = src[e];
    const int d = dst[e];
#pragma unroll
    for (int h = 0; h < HEADS; ++h) {
        const float att = e_edge[e * HEADS + h] / (exp_sum[d * HEADS + h] + EPS);
        const float v = Wh[s * HF + h * OUT_F + lane] * att;
        atomicAdd(&out[d * HF + h * OUT_F + lane], v);
    }
}

extern "C" void kernel_launch(void* const* d_in, const int* in_sizes, int n_in,
                              void* d_out, int out_size, void* d_ws, size_t ws_size,
                              hipStream_t stream) {
    const float* x      = (const float*)d_in[0];
    const int*   eidx   = (const int*)d_in[1];     // [2][E]
    const float* W      = (const float*)d_in[2];
    const float* a_src  = (const float*)d_in[3];
    const float* a_dst  = (const float*)d_in[4];
    float* out = (float*)d_out;

    const int* src = eidx;
    const int* dst = eidx + E_EDGES;

    // workspace layout (floats)
    float* ws = (float*)d_ws;
    float* Wh      = ws;                          // N*HF       = 12.8M
    float* esrc    = Wh + (size_t)N_NODES * HF;   // N*H        = 200K
    float* edst    = esrc + (size_t)N_NODES * HEADS;
    int*   emax    = (int*)(edst + (size_t)N_NODES * HEADS);
    float* exp_sum = (float*)emax + (size_t)N_NODES * HEADS;
    float* e_edge  = exp_sum + (size_t)N_NODES * HEADS;  // E*H = 3.2M

    // zero-init accumulators (ws/out are poisoned before every call)
    hipMemsetAsync(emax,    0, (size_t)N_NODES * HEADS * sizeof(int),   stream);
    hipMemsetAsync(exp_sum, 0, (size_t)N_NODES * HEADS * sizeof(float), stream);
    hipMemsetAsync(out,     0, (size_t)N_NODES * HF    * sizeof(float), stream);

    proj_kernel<<<N_NODES, 256, 0, stream>>>(x, W, a_src, a_dst, Wh, esrc, edst);

    const int eblocks = (E_EDGES + 255) / 256;
    edge_max_kernel<<<eblocks, 256, 0, stream>>>(src, dst, esrc, edst, e_edge, emax);
    edge_exp_kernel<<<eblocks, 256, 0, stream>>>(dst, e_edge, emax, exp_sum);

    const int ablocks = (E_EDGES * 64 + 255) / 256;  // one wave per edge
    aggregate_kernel<<<ablocks, 256, 0, stream>>>(src, dst, e_edge, exp_sum, Wh, out);
}

// Round 2
// 618.178 us; speedup vs baseline: 1.9107x; 1.9107x over previous
//
#include <hip/hip_runtime.h>

#define N_NODES 50000
#define E_EDGES 800000
#define IN_F    128
#define OUT_F   64
#define HEADS   4
#define HF      (HEADS * OUT_F)   // 256
#define NEG_SLOPE 0.2f
#define EPS     1e-8f
#define NPB     8                 // nodes per block in proj
#define NB_SCAN ((N_NODES + 255) / 256)   // 196 scan blocks

// ---------------- Kernel 1: per-head projection + attention logits ----------
// One block per 8 nodes. 256 threads: tid = h*64 + f. Wave w handles head w.
// W streamed once per block (131 KB from L2) amortized over 8 nodes.
__global__ __launch_bounds__(256) void proj_kernel(
    const float* __restrict__ x,      // [N][IN_F]
    const float* __restrict__ W,      // [H][IN_F][OUT_F]
    const float* __restrict__ a_src,  // [H][OUT_F]
    const float* __restrict__ a_dst,  // [H][OUT_F]
    float* __restrict__ Wh,           // [N][H][OUT_F]
    float* __restrict__ esrc,         // [N][H]
    float* __restrict__ edst)         // [N][H]
{
    __shared__ float xs[NPB][IN_F];   // 4 KB
    const int n0 = blockIdx.x * NPB;  // N/NPB = 6250 exact, no guard needed
    const int tid = threadIdx.x;

    // stage 8 x-rows (4 KB) with float4 loads
    ((float4*)xs)[tid] = ((const float4*)(x + (size_t)n0 * IN_F))[tid];
    __syncthreads();

    const int h = tid >> 6;
    const int f = tid & 63;
    const float* Wp = W + h * (IN_F * OUT_F) + f;

    float acc[NPB];
#pragma unroll
    for (int j = 0; j < NPB; ++j) acc[j] = 0.f;

#pragma unroll 2
    for (int k = 0; k < IN_F; k += 4) {
        const float w0 = Wp[(k + 0) * OUT_F];
        const float w1 = Wp[(k + 1) * OUT_F];
        const float w2 = Wp[(k + 2) * OUT_F];
        const float w3 = Wp[(k + 3) * OUT_F];
#pragma unroll
        for (int j = 0; j < NPB; ++j) {
            const float4 xv = *(const float4*)(&xs[j][k]);
            acc[j] += xv.x * w0 + xv.y * w1 + xv.z * w2 + xv.w * w3;
        }
    }

    const float asv = a_src[h * OUT_F + f];
    const float adv = a_dst[h * OUT_F + f];
#pragma unroll
    for (int j = 0; j < NPB; ++j) {
        Wh[(size_t)(n0 + j) * HF + tid] = acc[j];
        float ps = acc[j] * asv;
        float pd = acc[j] * adv;
#pragma unroll
        for (int off = 32; off > 0; off >>= 1) {
            ps += __shfl_down(ps, off);
            pd += __shfl_down(pd, off);
        }
        if (f == 0) {
            esrc[(n0 + j) * HEADS + h] = ps;
            edst[(n0 + j) * HEADS + h] = pd;
        }
    }
}

// ---------------- Kernel 2: edge logits + segment max + degree count --------
__global__ __launch_bounds__(256) void edge_max_kernel(
    const int* __restrict__ src,
    const int* __restrict__ dst,
    const float* __restrict__ esrc,   // [N][H]
    const float* __restrict__ edst,   // [N][H]
    float* __restrict__ e_edge,       // [E][H]
    int* __restrict__ emax,           // [N][H] float bits, init 0 == 0.0f
    int* __restrict__ cnt)            // [N] degree counts, init 0
{
    const int e = blockIdx.x * blockDim.x + threadIdx.x;
    if (e >= E_EDGES) return;
    const int s = src[e];
    const int d = dst[e];
    const float4 es = *(const float4*)(esrc + s * HEADS);
    const float4 ed = *(const float4*)(edst + d * HEADS);
    float ev[4] = { es.x + ed.x, es.y + ed.y, es.z + ed.z, es.w + ed.w };
    float4 outv;
    float* op = &outv.x;
#pragma unroll
    for (int h = 0; h < HEADS; ++h) {
        float v = ev[h];
        v = v > 0.f ? v : NEG_SLOPE * v;
        op[h] = v;
        if (v > 0.f) atomicMax(&emax[d * HEADS + h], __float_as_int(v));
    }
    *(float4*)(e_edge + (size_t)e * HEADS) = outv;
    atomicAdd(&cnt[d], 1);
}

// ---------------- Scan (3-phase hierarchical exclusive scan over cnt) ------
__device__ __forceinline__ int block_excl_scan_256(int v, int* ws) {
    const int tid = threadIdx.x;
    const int lane = tid & 63;
    const int wid = tid >> 6;
    int x = v;
#pragma unroll
    for (int off = 1; off < 64; off <<= 1) {
        int y = __shfl_up(x, off);
        if (lane >= off) x += y;
    }
    if (lane == 63) ws[wid] = x;
    __syncthreads();
    int wo = 0;
    if (wid > 0) wo += ws[0];
    if (wid > 1) wo += ws[1];
    if (wid > 2) wo += ws[2];
    return x - v + wo;   // exclusive prefix within block
}

__global__ __launch_bounds__(256) void scan1_kernel(
    int* __restrict__ cursor,   // in: counts; out: block-local exclusive scan
    int* __restrict__ bsum)     // [NB_SCAN] block totals
{
    __shared__ int ws[4];
    const int i = blockIdx.x * 256 + threadIdx.x;
    const int v = (i < N_NODES) ? cursor[i] : 0;
    const int excl = block_excl_scan_256(v, ws);
    if (i < N_NODES) cursor[i] = excl;
    if (threadIdx.x == 255) bsum[blockIdx.x] = excl + v;  // block total
}

__global__ __launch_bounds__(256) void scan2_kernel(int* __restrict__ bsum) {
    __shared__ int ws[4];
    const int tid = threadIdx.x;
    const int v = (tid < NB_SCAN) ? bsum[tid] : 0;
    const int excl = block_excl_scan_256(v, ws);
    if (tid < NB_SCAN) bsum[tid] = excl;
}

__global__ __launch_bounds__(256) void scan3_kernel(
    int* __restrict__ cursor,         // block-local excl -> global excl
    int* __restrict__ offs,           // [N+1] row offsets (copy of cursor)
    const int* __restrict__ bsum)
{
    const int i = blockIdx.x * 256 + threadIdx.x;
    if (i < N_NODES) {
        const int t = cursor[i] + bsum[blockIdx.x];
        cursor[i] = t;
        offs[i] = t;
    }
    if (i == 0) offs[N_NODES] = E_EDGES;
}

// ---------------- Kernel 3: exp + segment sum + CSR scatter -----------------
__global__ __launch_bounds__(256) void edge_exp_kernel(
    const int* __restrict__ dst,
    float* __restrict__ e_edge,       // in: e, out: exp_e
    const int* __restrict__ emax,     // [N][H] float bits
    float* __restrict__ exp_sum,      // [N][H], init 0
    int* __restrict__ cursor,         // [N] row cursors (consumed)
    int* __restrict__ csr_e)          // [E] edge ids grouped by dst
{
    const int e = blockIdx.x * blockDim.x + threadIdx.x;
    if (e >= E_EDGES) return;
    const int d = dst[e];
    float4 ev = *(float4*)(e_edge + (size_t)e * HEADS);
    float* ep = &ev.x;
#pragma unroll
    for (int h = 0; h < HEADS; ++h) {
        const float m = __int_as_float(emax[d * HEADS + h]);
        const float ex = __expf(ep[h] - m);
        ep[h] = ex;
        atomicAdd(&exp_sum[d * HEADS + h], ex);
    }
    *(float4*)(e_edge + (size_t)e * HEADS) = ev;
    const int pos = atomicAdd(&cursor[d], 1);
    csr_e[pos] = e;
}

// ---------------- Kernel 4: CSR aggregation, one wave per dst node ----------
__global__ __launch_bounds__(256) void aggregate_csr_kernel(
    const int* __restrict__ src,
    const int* __restrict__ offs,     // [N+1]
    const int* __restrict__ csr_e,    // [E]
    const float* __restrict__ e_edge, // exp_e [E][H]
    const float* __restrict__ exp_sum,// [N][H]
    const float* __restrict__ Wh,     // [N][H][OUT_F]
    float* __restrict__ out)          // [N][H][OUT_F], written exactly once
{
    const int wid = threadIdx.x >> 6;
    const int lane = threadIdx.x & 63;
    const int d = blockIdx.x * 4 + wid;   // 12500*4 = 50000 exact

    const int rs = offs[d];
    const int re = offs[d + 1];
    const float4 s4 = *(const float4*)(exp_sum + d * HEADS);
    const float r0 = 1.f / (s4.x + EPS);
    const float r1 = 1.f / (s4.y + EPS);
    const float r2 = 1.f / (s4.z + EPS);
    const float r3 = 1.f / (s4.w + EPS);

    float a0 = 0.f, a1 = 0.f, a2 = 0.f, a3 = 0.f;
    int idx = rs;
    for (; idx + 1 < re; idx += 2) {
        const int e0 = csr_e[idx];
        const int e1 = csr_e[idx + 1];
        const int s0 = src[e0];
        const int s1 = src[e1];
        const float4 x0 = *(const float4*)(e_edge + (size_t)e0 * HEADS);
        const float4 x1 = *(const float4*)(e_edge + (size_t)e1 * HEADS);
        const float* w0 = Wh + (size_t)s0 * HF + lane;
        const float* w1 = Wh + (size_t)s1 * HF + lane;
        a0 += (x0.x * r0) * w0[0];
        a1 += (x0.y * r1) * w0[64];
        a2 += (x0.z * r2) * w0[128];
        a3 += (x0.w * r3) * w0[192];
        a0 += (x1.x * r0) * w1[0];
        a1 += (x1.y * r1) * w1[64];
        a2 += (x1.z * r2) * w1[128];
        a3 += (x1.w * r3) * w1[192];
    }
    if (idx < re) {
        const int e0 = csr_e[idx];
        const int s0 = src[e0];
        const float4 x0 = *(const float4*)(e_edge + (size_t)e0 * HEADS);
        const float* w0 = Wh + (size_t)s0 * HF + lane;
        a0 += (x0.x * r0) * w0[0];
        a1 += (x0.y * r1) * w0[64];
        a2 += (x0.z * r2) * w0[128];
        a3 += (x0.w * r3) * w0[192];
    }

    float* op = out + (size_t)d * HF + lane;
    op[0]   = a0;
    op[64]  = a1;
    op[128] = a2;
    op[192] = a3;
}

extern "C" void kernel_launch(void* const* d_in, const int* in_sizes, int n_in,
                              void* d_out, int out_size, void* d_ws, size_t ws_size,
                              hipStream_t stream) {
    const float* x      = (const float*)d_in[0];
    const int*   eidx   = (const int*)d_in[1];     // [2][E]
    const float* W      = (const float*)d_in[2];
    const float* a_src  = (const float*)d_in[3];
    const float* a_dst  = (const float*)d_in[4];
    float* out = (float*)d_out;

    const int* src = eidx;
    const int* dst = eidx + E_EDGES;

    // workspace layout
    float* ws = (float*)d_ws;
    float* Wh      = ws;                                   // N*HF   (51.2 MB)
    float* esrc    = Wh + (size_t)N_NODES * HF;            // N*H
    float* edst    = esrc + (size_t)N_NODES * HEADS;       // N*H
    int*   emax    = (int*)(edst + (size_t)N_NODES * HEADS);          // N*H
    float* exp_sum = (float*)emax + (size_t)N_NODES * HEADS;          // N*H
    float* e_edge  = exp_sum + (size_t)N_NODES * HEADS;    // E*H    (12.8 MB)
    int*   cursor  = (int*)(e_edge + (size_t)E_EDGES * HEADS);        // N
    int*   offs    = cursor + N_NODES;                     // N+1
    int*   bsum    = offs + N_NODES + 1;                   // 256
    int*   csr_e   = bsum + 256;                           // E (3.2 MB)

    hipMemsetAsync(emax,    0, (size_t)N_NODES * HEADS * sizeof(int),   stream);
    hipMemsetAsync(exp_sum, 0, (size_t)N_NODES * HEADS * sizeof(float), stream);
    hipMemsetAsync(cursor,  0, (size_t)N_NODES * sizeof(int),           stream);

    proj_kernel<<<N_NODES / NPB, 256, 0, stream>>>(x, W, a_src, a_dst, Wh, esrc, edst);

    const int eblocks = (E_EDGES + 255) / 256;
    edge_max_kernel<<<eblocks, 256, 0, stream>>>(src, dst, esrc, edst, e_edge, emax, cursor);

    scan1_kernel<<<NB_SCAN, 256, 0, stream>>>(cursor, bsum);
    scan2_kernel<<<1, 256, 0, stream>>>(bsum);
    scan3_kernel<<<NB_SCAN, 256, 0, stream>>>(cursor, offs, bsum);

    edge_exp_kernel<<<eblocks, 256, 0, stream>>>(dst, e_edge, emax, exp_sum, cursor, csr_e);

    aggregate_csr_kernel<<<N_NODES / 4, 256, 0, stream>>>(src, offs, csr_e, e_edge, exp_sum, Wh, out);
}

// Round 3
// 387.321 us; speedup vs baseline: 3.0495x; 1.5960x over previous
//
#include <hip/hip_runtime.h>

#define N_NODES 50000
#define E_EDGES 800000
#define IN_F    128
#define OUT_F   64
#define HEADS   4
#define HF      (HEADS * OUT_F)   // 256
#define NEG_SLOPE 0.2f
#define EPS     1e-8f
#define NPB     8                 // nodes per block in proj
#define NB_SCAN ((N_NODES + 255) / 256)   // 196 scan blocks

// ---------------- Kernel 1: per-head projection + attention logits ----------
// One block per 8 nodes. 256 threads: tid = h*64 + f. Wave w handles head w.
// Wh stored transposed as [N][OUT_F][HEADS] so the aggregate kernel reads one
// float4 (all 4 heads) per lane per edge.
__global__ __launch_bounds__(256) void proj_kernel(
    const float* __restrict__ x,      // [N][IN_F]
    const float* __restrict__ W,      // [H][IN_F][OUT_F]
    const float* __restrict__ a_src,  // [H][OUT_F]
    const float* __restrict__ a_dst,  // [H][OUT_F]
    float* __restrict__ Wh,           // [N][OUT_F][HEADS]  (transposed!)
    float* __restrict__ esrc,         // [N][H]
    float* __restrict__ edst)         // [N][H]
{
    __shared__ float xs[NPB][IN_F];   // 4 KB
    const int n0 = blockIdx.x * NPB;  // N/NPB = 6250 exact
    const int tid = threadIdx.x;

    ((float4*)xs)[tid] = ((const float4*)(x + (size_t)n0 * IN_F))[tid];
    __syncthreads();

    const int h = tid >> 6;
    const int f = tid & 63;
    const float* Wp = W + h * (IN_F * OUT_F) + f;

    float acc[NPB];
#pragma unroll
    for (int j = 0; j < NPB; ++j) acc[j] = 0.f;

#pragma unroll 2
    for (int k = 0; k < IN_F; k += 4) {
        const float w0 = Wp[(k + 0) * OUT_F];
        const float w1 = Wp[(k + 1) * OUT_F];
        const float w2 = Wp[(k + 2) * OUT_F];
        const float w3 = Wp[(k + 3) * OUT_F];
#pragma unroll
        for (int j = 0; j < NPB; ++j) {
            const float4 xv = *(const float4*)(&xs[j][k]);
            acc[j] += xv.x * w0 + xv.y * w1 + xv.z * w2 + xv.w * w3;
        }
    }

    const float asv = a_src[h * OUT_F + f];
    const float adv = a_dst[h * OUT_F + f];
#pragma unroll
    for (int j = 0; j < NPB; ++j) {
        // transposed store: [node][f][h]
        Wh[(size_t)(n0 + j) * HF + (f << 2) + h] = acc[j];
        float ps = acc[j] * asv;
        float pd = acc[j] * adv;
#pragma unroll
        for (int off = 32; off > 0; off >>= 1) {
            ps += __shfl_down(ps, off);
            pd += __shfl_down(pd, off);
        }
        if (f == 0) {
            esrc[(n0 + j) * HEADS + h] = ps;
            edst[(n0 + j) * HEADS + h] = pd;
        }
    }
}

// ---------------- Kernel 2: degree count ------------------------------------
__global__ __launch_bounds__(256) void count_kernel(
    const int* __restrict__ dst,
    int* __restrict__ cnt)            // [N], init 0
{
    const int e = blockIdx.x * 256 + threadIdx.x;
    if (e < E_EDGES) atomicAdd(&cnt[dst[e]], 1);
}

// ---------------- Scan (3-phase hierarchical exclusive scan) ----------------
__device__ __forceinline__ int block_excl_scan_256(int v, int* ws) {
    const int tid = threadIdx.x;
    const int lane = tid & 63;
    const int wid = tid >> 6;
    int x = v;
#pragma unroll
    for (int off = 1; off < 64; off <<= 1) {
        int y = __shfl_up(x, off);
        if (lane >= off) x += y;
    }
    if (lane == 63) ws[wid] = x;
    __syncthreads();
    int wo = 0;
    if (wid > 0) wo += ws[0];
    if (wid > 1) wo += ws[1];
    if (wid > 2) wo += ws[2];
    return x - v + wo;
}

__global__ __launch_bounds__(256) void scan1_kernel(
    int* __restrict__ cursor, int* __restrict__ bsum)
{
    __shared__ int ws[4];
    const int i = blockIdx.x * 256 + threadIdx.x;
    const int v = (i < N_NODES) ? cursor[i] : 0;
    const int excl = block_excl_scan_256(v, ws);
    if (i < N_NODES) cursor[i] = excl;
    if (threadIdx.x == 255) bsum[blockIdx.x] = excl + v;
}

__global__ __launch_bounds__(256) void scan2_kernel(int* __restrict__ bsum) {
    __shared__ int ws[4];
    const int tid = threadIdx.x;
    const int v = (tid < NB_SCAN) ? bsum[tid] : 0;
    const int excl = block_excl_scan_256(v, ws);
    if (tid < NB_SCAN) bsum[tid] = excl;
}

__global__ __launch_bounds__(256) void scan3_kernel(
    int* __restrict__ cursor, int* __restrict__ offs,
    const int* __restrict__ bsum)
{
    const int i = blockIdx.x * 256 + threadIdx.x;
    if (i < N_NODES) {
        const int t = cursor[i] + bsum[blockIdx.x];
        cursor[i] = t;
        offs[i] = t;
    }
    if (i == 0) offs[N_NODES] = E_EDGES;
}

// ---------------- Kernel 3: CSR scatter (store src ids grouped by dst) ------
__global__ __launch_bounds__(256) void scatter_kernel(
    const int* __restrict__ src,
    const int* __restrict__ dst,
    int* __restrict__ cursor,         // consumed
    int* __restrict__ csr_src)        // [E] src node ids grouped by dst
{
    const int e = blockIdx.x * 256 + threadIdx.x;
    if (e >= E_EDGES) return;
    const int pos = atomicAdd(&cursor[dst[e]], 1);
    csr_src[pos] = src[e];
}

// ---------------- Kernel 4: fused softmax + aggregation ---------------------
// One wave per dst node. No max subtraction: reference's e_max=max(seg_max,0)
// makes exp(e)/(sum+EPS) equivalent within ~1e-8 rel (logits bounded ~±13).
__global__ __launch_bounds__(256) void aggregate_kernel(
    const int* __restrict__ offs,     // [N+1]
    const int* __restrict__ csr_src,  // [E]
    const float* __restrict__ esrc,   // [N][H]
    const float* __restrict__ edst,   // [N][H]
    const float* __restrict__ Wh,     // [N][OUT_F][HEADS]
    float* __restrict__ out)          // [N][H*OUT_F]
{
    const int wid = threadIdx.x >> 6;
    const int lane = threadIdx.x & 63;
    const int d = blockIdx.x * 4 + wid;   // 12500*4 = 50000 exact

    const int rs = offs[d];
    const int re = offs[d + 1];
    const float4 ed4 = *(const float4*)(edst + d * HEADS);

    float o0 = 0.f, o1 = 0.f, o2 = 0.f, o3 = 0.f;
    float l0 = 0.f, l1 = 0.f, l2 = 0.f, l3 = 0.f;

    for (int base = rs; base < re; base += 64) {
        const int len = re - base < 64 ? re - base : 64;
        int s = 0;
        float p0 = 0.f, p1 = 0.f, p2 = 0.f, p3 = 0.f;
        if (lane < len) {
            s = csr_src[base + lane];
            const float4 es4 = *(const float4*)(esrc + s * HEADS);
            float v0 = es4.x + ed4.x; v0 = v0 > 0.f ? v0 : NEG_SLOPE * v0;
            float v1 = es4.y + ed4.y; v1 = v1 > 0.f ? v1 : NEG_SLOPE * v1;
            float v2 = es4.z + ed4.z; v2 = v2 > 0.f ? v2 : NEG_SLOPE * v2;
            float v3 = es4.w + ed4.w; v3 = v3 > 0.f ? v3 : NEG_SLOPE * v3;
            p0 = __expf(v0); p1 = __expf(v1);
            p2 = __expf(v2); p3 = __expf(v3);
        }
        l0 += p0; l1 += p1; l2 += p2; l3 += p3;

        for (int i = 0; i < len; ++i) {
            const int   si = __shfl(s, i);
            const float q0 = __shfl(p0, i);
            const float q1 = __shfl(p1, i);
            const float q2 = __shfl(p2, i);
            const float q3 = __shfl(p3, i);
            const float4 w4 = *(const float4*)(Wh + (size_t)si * HF + (lane << 2));
            o0 += q0 * w4.x;
            o1 += q1 * w4.y;
            o2 += q2 * w4.z;
            o3 += q3 * w4.w;
        }
    }

    // all-reduce l across the wave
#pragma unroll
    for (int m = 1; m < 64; m <<= 1) {
        l0 += __shfl_xor(l0, m);
        l1 += __shfl_xor(l1, m);
        l2 += __shfl_xor(l2, m);
        l3 += __shfl_xor(l3, m);
    }
    const float r0 = 1.f / (l0 + EPS);
    const float r1 = 1.f / (l1 + EPS);
    const float r2 = 1.f / (l2 + EPS);
    const float r3 = 1.f / (l3 + EPS);

    float* op = out + (size_t)d * HF + lane;
    op[0]   = o0 * r0;
    op[64]  = o1 * r1;
    op[128] = o2 * r2;
    op[192] = o3 * r3;
}

extern "C" void kernel_launch(void* const* d_in, const int* in_sizes, int n_in,
                              void* d_out, int out_size, void* d_ws, size_t ws_size,
                              hipStream_t stream) {
    const float* x      = (const float*)d_in[0];
    const int*   eidx   = (const int*)d_in[1];     // [2][E]
    const float* W      = (const float*)d_in[2];
    const float* a_src  = (const float*)d_in[3];
    const float* a_dst  = (const float*)d_in[4];
    float* out = (float*)d_out;

    const int* src = eidx;
    const int* dst = eidx + E_EDGES;

    // workspace layout
    float* ws = (float*)d_ws;
    float* Wh     = ws;                                    // N*HF (51.2 MB)
    float* esrc   = Wh + (size_t)N_NODES * HF;             // N*H
    float* edst   = esrc + (size_t)N_NODES * HEADS;        // N*H
    int*   cursor = (int*)(edst + (size_t)N_NODES * HEADS);// N
    int*   offs   = cursor + N_NODES;                      // N+1
    int*   bsum   = offs + N_NODES + 1;                    // 256
    int*   csr_src= bsum + 256;                            // E (3.2 MB)

    hipMemsetAsync(cursor, 0, (size_t)N_NODES * sizeof(int), stream);

    proj_kernel<<<N_NODES / NPB, 256, 0, stream>>>(x, W, a_src, a_dst, Wh, esrc, edst);

    const int eblocks = (E_EDGES + 255) / 256;
    count_kernel<<<eblocks, 256, 0, stream>>>(dst, cursor);

    scan1_kernel<<<NB_SCAN, 256, 0, stream>>>(cursor, bsum);
    scan2_kernel<<<1, 256, 0, stream>>>(bsum);
    scan3_kernel<<<NB_SCAN, 256, 0, stream>>>(cursor, offs, bsum);

    scatter_kernel<<<eblocks, 256, 0, stream>>>(src, dst, cursor, csr_src);

    aggregate_kernel<<<N_NODES / 4, 256, 0, stream>>>(offs, csr_src, esrc, edst, Wh, out);
}

// Round 4
// 299.512 us; speedup vs baseline: 3.9436x; 1.2932x over previous
//
#include <hip/hip_runtime.h>
#include <hip/hip_bf16.h>

#define N_NODES 50000
#define E_EDGES 800000
#define IN_F    128
#define OUT_F   64
#define HEADS   4
#define HF      (HEADS * OUT_F)   // 256
#define NEG_SLOPE 0.2f
#define EPS     1e-8f
#define NPB     8                 // nodes per block in proj
#define NB_SCAN ((N_NODES + 255) / 256)   // 196 scan blocks

// ---------------- Kernel 1: projection + logits + fused degree count --------
// One block per 8 nodes. 256 threads: tid = h*64 + f. Wave w handles head w.
// x rows read via wave-uniform global loads (no LDS). Wh stored bf16,
// transposed [N][OUT_F][HEADS] so aggregate reads one ushort4 per lane/edge.
// Also: threads 0..127 count edge degrees (6250 blocks * 128 = 800000 exact).
__global__ __launch_bounds__(256) void proj_kernel(
    const float* __restrict__ x,      // [N][IN_F]
    const float* __restrict__ W,      // [H][IN_F][OUT_F]
    const float* __restrict__ a_src,  // [H][OUT_F]
    const float* __restrict__ a_dst,  // [H][OUT_F]
    const int* __restrict__ dst,      // [E]
    unsigned short* __restrict__ Whb, // [N][OUT_F][HEADS] bf16 bits
    float* __restrict__ esrc,         // [N][H]
    float* __restrict__ edst,         // [N][H]
    int* __restrict__ cnt)            // [N], init 0
{
    const int tid = threadIdx.x;

    // fused degree count: fire-and-forget atomics, overlap with FMA loop
    if (tid < 128) {
        const int e = blockIdx.x * 128 + tid;
        atomicAdd(&cnt[dst[e]], 1);
    }

    const int n0 = blockIdx.x * NPB;  // N/NPB = 6250 exact
    const int h = tid >> 6;
    const int f = tid & 63;
    const float* Wp = W + h * (IN_F * OUT_F) + f;
    const float* xp = x + (size_t)n0 * IN_F;

    float acc[NPB];
#pragma unroll
    for (int j = 0; j < NPB; ++j) acc[j] = 0.f;

#pragma unroll 2
    for (int k = 0; k < IN_F; k += 4) {
        const float w0 = Wp[(k + 0) * OUT_F];
        const float w1 = Wp[(k + 1) * OUT_F];
        const float w2 = Wp[(k + 2) * OUT_F];
        const float w3 = Wp[(k + 3) * OUT_F];
#pragma unroll
        for (int j = 0; j < NPB; ++j) {
            const float4 xv = *(const float4*)(xp + j * IN_F + k);  // uniform
            acc[j] += xv.x * w0 + xv.y * w1 + xv.z * w2 + xv.w * w3;
        }
    }

    const float asv = a_src[h * OUT_F + f];
    const float adv = a_dst[h * OUT_F + f];
#pragma unroll
    for (int j = 0; j < NPB; ++j) {
        // bf16 RNE store, transposed layout [node][f][h]
        Whb[(size_t)(n0 + j) * HF + (f << 2) + h] =
            __hip_bfloat16_raw(__float2bfloat16(acc[j])).x;
        float ps = acc[j] * asv;
        float pd = acc[j] * adv;
#pragma unroll
        for (int off = 32; off > 0; off >>= 1) {
            ps += __shfl_down(ps, off);
            pd += __shfl_down(pd, off);
        }
        if (f == 0) {
            esrc[(n0 + j) * HEADS + h] = ps;
            edst[(n0 + j) * HEADS + h] = pd;
        }
    }
}

// ---------------- Scan (3-phase hierarchical exclusive scan) ----------------
__device__ __forceinline__ int block_excl_scan_256(int v, int* ws) {
    const int tid = threadIdx.x;
    const int lane = tid & 63;
    const int wid = tid >> 6;
    int x = v;
#pragma unroll
    for (int off = 1; off < 64; off <<= 1) {
        int y = __shfl_up(x, off);
        if (lane >= off) x += y;
    }
    if (lane == 63) ws[wid] = x;
    __syncthreads();
    int wo = 0;
    if (wid > 0) wo += ws[0];
    if (wid > 1) wo += ws[1];
    if (wid > 2) wo += ws[2];
    return x - v + wo;
}

__global__ __launch_bounds__(256) void scan1_kernel(
    int* __restrict__ cursor, int* __restrict__ bsum)
{
    __shared__ int ws[4];
    const int i = blockIdx.x * 256 + threadIdx.x;
    const int v = (i < N_NODES) ? cursor[i] : 0;
    const int excl = block_excl_scan_256(v, ws);
    if (i < N_NODES) cursor[i] = excl;
    if (threadIdx.x == 255) bsum[blockIdx.x] = excl + v;
}

__global__ __launch_bounds__(256) void scan2_kernel(int* __restrict__ bsum) {
    __shared__ int ws[4];
    const int tid = threadIdx.x;
    const int v = (tid < NB_SCAN) ? bsum[tid] : 0;
    const int excl = block_excl_scan_256(v, ws);
    if (tid < NB_SCAN) bsum[tid] = excl;
}

__global__ __launch_bounds__(256) void scan3_kernel(
    int* __restrict__ cursor, int* __restrict__ offs,
    const int* __restrict__ bsum)
{
    const int i = blockIdx.x * 256 + threadIdx.x;
    if (i < N_NODES) {
        const int t = cursor[i] + bsum[blockIdx.x];
        cursor[i] = t;
        offs[i] = t;
    }
    if (i == 0) offs[N_NODES] = E_EDGES;
}

// ---------------- Kernel 2: CSR scatter (store src ids grouped by dst) ------
__global__ __launch_bounds__(256) void scatter_kernel(
    const int* __restrict__ src,
    const int* __restrict__ dst,
    int* __restrict__ cursor,         // consumed
    int* __restrict__ csr_src)        // [E] src node ids grouped by dst
{
    const int e = blockIdx.x * 256 + threadIdx.x;
    if (e >= E_EDGES) return;
    const int pos = atomicAdd(&cursor[dst[e]], 1);
    csr_src[pos] = src[e];
}

// ---------------- Kernel 3: fused softmax + aggregation ---------------------
// One wave per dst node. No max subtraction: reference's e_max=max(seg_max,0)
// makes exp(e)/(sum+EPS) equivalent within ~1e-8 rel (logits bounded ~±13).
__global__ __launch_bounds__(256) void aggregate_kernel(
    const int* __restrict__ offs,     // [N+1]
    const int* __restrict__ csr_src,  // [E]
    const float* __restrict__ esrc,   // [N][H]
    const float* __restrict__ edst,   // [N][H]
    const unsigned short* __restrict__ Whb, // [N][OUT_F][HEADS] bf16 bits
    float* __restrict__ out)          // [N][H*OUT_F]
{
    const int wid = threadIdx.x >> 6;
    const int lane = threadIdx.x & 63;
    const int d = blockIdx.x * 4 + wid;   // 12500*4 = 50000 exact

    const int rs = offs[d];
    const int re = offs[d + 1];
    const float4 ed4 = *(const float4*)(edst + d * HEADS);

    float o0 = 0.f, o1 = 0.f, o2 = 0.f, o3 = 0.f;
    float l0 = 0.f, l1 = 0.f, l2 = 0.f, l3 = 0.f;

    for (int base = rs; base < re; base += 64) {
        const int len = re - base < 64 ? re - base : 64;
        int s = 0;
        float p0 = 0.f, p1 = 0.f, p2 = 0.f, p3 = 0.f;
        if (lane < len) {
            s = csr_src[base + lane];
            const float4 es4 = *(const float4*)(esrc + s * HEADS);
            float v0 = es4.x + ed4.x; v0 = v0 > 0.f ? v0 : NEG_SLOPE * v0;
            float v1 = es4.y + ed4.y; v1 = v1 > 0.f ? v1 : NEG_SLOPE * v1;
            float v2 = es4.z + ed4.z; v2 = v2 > 0.f ? v2 : NEG_SLOPE * v2;
            float v3 = es4.w + ed4.w; v3 = v3 > 0.f ? v3 : NEG_SLOPE * v3;
            p0 = __expf(v0); p1 = __expf(v1);
            p2 = __expf(v2); p3 = __expf(v3);
        }
        l0 += p0; l1 += p1; l2 += p2; l3 += p3;

        for (int i = 0; i < len; ++i) {
            const int   si = __shfl(s, i);
            const float q0 = __shfl(p0, i);
            const float q1 = __shfl(p1, i);
            const float q2 = __shfl(p2, i);
            const float q3 = __shfl(p3, i);
            const ushort4 w4 = *(const ushort4*)(Whb + (size_t)si * HF + (lane << 2));
            o0 += q0 * __uint_as_float((unsigned)w4.x << 16);
            o1 += q1 * __uint_as_float((unsigned)w4.y << 16);
            o2 += q2 * __uint_as_float((unsigned)w4.z << 16);
            o3 += q3 * __uint_as_float((unsigned)w4.w << 16);
        }
    }

    // all-reduce l across the wave
#pragma unroll
    for (int m = 1; m < 64; m <<= 1) {
        l0 += __shfl_xor(l0, m);
        l1 += __shfl_xor(l1, m);
        l2 += __shfl_xor(l2, m);
        l3 += __shfl_xor(l3, m);
    }
    const float r0 = 1.f / (l0 + EPS);
    const float r1 = 1.f / (l1 + EPS);
    const float r2 = 1.f / (l2 + EPS);
    const float r3 = 1.f / (l3 + EPS);

    float* op = out + (size_t)d * HF + lane;
    op[0]   = o0 * r0;
    op[64]  = o1 * r1;
    op[128] = o2 * r2;
    op[192] = o3 * r3;
}

extern "C" void kernel_launch(void* const* d_in, const int* in_sizes, int n_in,
                              void* d_out, int out_size, void* d_ws, size_t ws_size,
                              hipStream_t stream) {
    const float* x      = (const float*)d_in[0];
    const int*   eidx   = (const int*)d_in[1];     // [2][E]
    const float* W      = (const float*)d_in[2];
    const float* a_src  = (const float*)d_in[3];
    const float* a_dst  = (const float*)d_in[4];
    float* out = (float*)d_out;

    const int* src = eidx;
    const int* dst = eidx + E_EDGES;

    // workspace layout
    unsigned short* Whb = (unsigned short*)d_ws;                  // N*HF bf16 (25.6 MB)
    float* esrc   = (float*)(Whb + (size_t)N_NODES * HF);         // N*H
    float* edst   = esrc + (size_t)N_NODES * HEADS;               // N*H
    int*   cursor = (int*)(edst + (size_t)N_NODES * HEADS);       // N
    int*   offs   = cursor + N_NODES;                             // N+1
    int*   bsum   = offs + N_NODES + 1;                           // 256
    int*   csr_src= bsum + 256;                                   // E (3.2 MB)

    hipMemsetAsync(cursor, 0, (size_t)N_NODES * sizeof(int), stream);

    proj_kernel<<<N_NODES / NPB, 256, 0, stream>>>(x, W, a_src, a_dst, dst,
                                                   Whb, esrc, edst, cursor);

    scan1_kernel<<<NB_SCAN, 256, 0, stream>>>(cursor, bsum);
    scan2_kernel<<<1, 256, 0, stream>>>(bsum);
    scan3_kernel<<<NB_SCAN, 256, 0, stream>>>(cursor, offs, bsum);

    const int eblocks = (E_EDGES + 255) / 256;
    scatter_kernel<<<eblocks, 256, 0, stream>>>(src, dst, cursor, csr_src);

    aggregate_kernel<<<N_NODES / 4, 256, 0, stream>>>(offs, csr_src, esrc, edst, Whb, out);
}

// Round 5
// 259.330 us; speedup vs baseline: 4.5546x; 1.1549x over previous
//
#include <hip/hip_runtime.h>
#include <hip/hip_bf16.h>

#define N_NODES 50000
#define E_EDGES 800000
#define IN_F    128
#define OUT_F   64
#define HEADS   4
#define HF      (HEADS * OUT_F)   // 256
#define NEG_SLOPE 0.2f
#define EPS     1e-8f
#define NB_SCAN ((N_NODES + 255) / 256)   // 196 scan blocks

typedef __attribute__((ext_vector_type(8))) short bf16x8;
typedef __attribute__((ext_vector_type(4))) float f32x4;

__device__ __forceinline__ unsigned short f2bf(float f) {
    return __hip_bfloat16_raw(__float2bfloat16(f)).x;
}

// ---------------- Kernel 0: W -> bf16, transposed [H][OUT_F][IN_F] ----------
__global__ __launch_bounds__(256) void wcvt_kernel(
    const float* __restrict__ W,      // [H][IN_F][OUT_F]
    short* __restrict__ Wtb)          // [H][OUT_F][IN_F] bf16 bits
{
    const int i = blockIdx.x * 256 + threadIdx.x;   // 32768 total
    const int h  = i >> 13;
    const int fl = (i >> 7) & 63;
    const int k  = i & 127;
    Wtb[i] = (short)f2bf(W[h * (IN_F * OUT_F) + k * OUT_F + fl]);
}

// ---------------- Kernel 1: MFMA projection + logits + fused count ----------
// One block per 16 nodes (3125 blocks), 4 waves; wave w = head w.
// C = X[16x128] * W_h[128x64] via 16 MFMAs (4 n-tiles x 4 k-steps).
__global__ __launch_bounds__(256) void proj_kernel(
    const float* __restrict__ x,      // [N][IN_F]
    const short* __restrict__ Wtb,    // [H][OUT_F][IN_F] bf16
    const float* __restrict__ a_src,  // [H][OUT_F]
    const float* __restrict__ a_dst,  // [H][OUT_F]
    const int* __restrict__ dst,      // [E]
    unsigned short* __restrict__ Whb, // [N][OUT_F*HEADS] bf16 ([n][f*4+h])
    float* __restrict__ esrc,         // [N][H]
    float* __restrict__ edst,         // [N][H]
    int* __restrict__ cnt)            // [N], init 0
{
    __shared__ short xs[16][136];            // bf16 x tile, 16B-aligned rows
    __shared__ unsigned short ot[16][256];   // output transpose buffer

    const int tid = threadIdx.x;
    const int n0 = blockIdx.x * 16;          // 3125 * 16 = 50000 exact

    // fused degree count: 3125 * 256 = 800000 exact
    atomicAdd(&cnt[dst[blockIdx.x * 256 + tid]], 1);

    // stage x tile -> bf16 LDS. thread t: row t>>4, k-base (t&15)*8
    {
        const int row = tid >> 4;
        const int kb = (tid & 15) * 8;
        const float* xp = x + (size_t)(n0 + row) * IN_F + kb;
        const float4 x0 = *(const float4*)(xp);
        const float4 x1 = *(const float4*)(xp + 4);
        bf16x8 v;
        v[0] = (short)f2bf(x0.x); v[1] = (short)f2bf(x0.y);
        v[2] = (short)f2bf(x0.z); v[3] = (short)f2bf(x0.w);
        v[4] = (short)f2bf(x1.x); v[5] = (short)f2bf(x1.y);
        v[6] = (short)f2bf(x1.z); v[7] = (short)f2bf(x1.w);
        *(bf16x8*)&xs[row][kb] = v;
    }
    __syncthreads();

    const int h = tid >> 6;       // wave id = head
    const int lane = tid & 63;
    const int c = lane & 15;      // col-within-tile / A-row m
    const int quad = lane >> 4;

    // A fragments: a[ks][j] = X[m=c][k=ks*32+quad*8+j]
    bf16x8 a[4];
#pragma unroll
    for (int ks = 0; ks < 4; ++ks)
        a[ks] = *(const bf16x8*)&xs[c][ks * 32 + quad * 8];

    f32x4 acc[4];
#pragma unroll
    for (int nt = 0; nt < 4; ++nt) acc[nt] = (f32x4){0.f, 0.f, 0.f, 0.f};

    const short* Wh_head = Wtb + (h << 13);   // head's [64][128]
#pragma unroll
    for (int nt = 0; nt < 4; ++nt) {
        const short* wrow = Wh_head + ((nt * 16 + c) << 7) + (quad << 3);
#pragma unroll
        for (int ks = 0; ks < 4; ++ks) {
            const bf16x8 b = *(const bf16x8*)(wrow + (ks << 5));
            acc[nt] = __builtin_amdgcn_mfma_f32_16x16x32_bf16(a[ks], b, acc[nt], 0, 0, 0);
        }
    }

    // ---- logits: e[m] = sum_f C[m][f]*a[f]; lane holds rows quad*4+r, col nt*16+c
    float ps[4] = {0.f, 0.f, 0.f, 0.f};
    float pd[4] = {0.f, 0.f, 0.f, 0.f};
#pragma unroll
    for (int nt = 0; nt < 4; ++nt) {
        const float as = a_src[h * OUT_F + nt * 16 + c];
        const float ad = a_dst[h * OUT_F + nt * 16 + c];
#pragma unroll
        for (int r = 0; r < 4; ++r) {
            ps[r] += acc[nt][r] * as;
            pd[r] += acc[nt][r] * ad;
        }
    }
#pragma unroll
    for (int m = 1; m < 16; m <<= 1) {
#pragma unroll
        for (int r = 0; r < 4; ++r) {
            ps[r] += __shfl_xor(ps[r], m);
            pd[r] += __shfl_xor(pd[r], m);
        }
    }
    if (c == 0) {
#pragma unroll
        for (int r = 0; r < 4; ++r) {
            const int n = n0 + quad * 4 + r;
            esrc[n * HEADS + h] = ps[r];
            edst[n * HEADS + h] = pd[r];
        }
    }

    // ---- Wh store: bf16 via LDS transpose, then coalesced global store
#pragma unroll
    for (int nt = 0; nt < 4; ++nt) {
#pragma unroll
        for (int r = 0; r < 4; ++r)
            ot[quad * 4 + r][(nt * 16 + c) * 4 + h] = f2bf(acc[nt][r]);
    }
    __syncthreads();
    {
        // 16*256 bf16 = 8192 B; thread t stores 32 B contiguous
        const unsigned short* sp = &ot[0][0] + tid * 16;
        unsigned short* gp = Whb + (size_t)n0 * HF + tid * 16;
        *(int4*)(gp)     = *(const int4*)(sp);
        *(int4*)(gp + 8) = *(const int4*)(sp + 8);
    }
}

// ---------------- Scan (3-phase hierarchical exclusive scan) ----------------
__device__ __forceinline__ int block_excl_scan_256(int v, int* ws) {
    const int tid = threadIdx.x;
    const int lane = tid & 63;
    const int wid = tid >> 6;
    int x = v;
#pragma unroll
    for (int off = 1; off < 64; off <<= 1) {
        int y = __shfl_up(x, off);
        if (lane >= off) x += y;
    }
    if (lane == 63) ws[wid] = x;
    __syncthreads();
    int wo = 0;
    if (wid > 0) wo += ws[0];
    if (wid > 1) wo += ws[1];
    if (wid > 2) wo += ws[2];
    return x - v + wo;
}

__global__ __launch_bounds__(256) void scan1_kernel(
    int* __restrict__ cursor, int* __restrict__ bsum)
{
    __shared__ int ws[4];
    const int i = blockIdx.x * 256 + threadIdx.x;
    const int v = (i < N_NODES) ? cursor[i] : 0;
    const int excl = block_excl_scan_256(v, ws);
    if (i < N_NODES) cursor[i] = excl;
    if (threadIdx.x == 255) bsum[blockIdx.x] = excl + v;
}

__global__ __launch_bounds__(256) void scan2_kernel(int* __restrict__ bsum) {
    __shared__ int ws[4];
    const int tid = threadIdx.x;
    const int v = (tid < NB_SCAN) ? bsum[tid] : 0;
    const int excl = block_excl_scan_256(v, ws);
    if (tid < NB_SCAN) bsum[tid] = excl;
}

__global__ __launch_bounds__(256) void scan3_kernel(
    int* __restrict__ cursor, int* __restrict__ offs,
    const int* __restrict__ bsum)
{
    const int i = blockIdx.x * 256 + threadIdx.x;
    if (i < N_NODES) {
        const int t = cursor[i] + bsum[blockIdx.x];
        cursor[i] = t;
        offs[i] = t;
    }
    if (i == 0) offs[N_NODES] = E_EDGES;
}

// ---------------- Kernel 2: CSR scatter (store src ids grouped by dst) ------
__global__ __launch_bounds__(256) void scatter_kernel(
    const int* __restrict__ src,
    const int* __restrict__ dst,
    int* __restrict__ cursor,         // consumed
    int* __restrict__ csr_src)        // [E] src node ids grouped by dst
{
    const int e = blockIdx.x * 256 + threadIdx.x;
    if (e >= E_EDGES) return;
    const int pos = atomicAdd(&cursor[dst[e]], 1);
    csr_src[pos] = src[e];
}

// ---------------- Kernel 3: fused softmax + aggregation ---------------------
// One wave per dst node. No max subtraction: reference's e_max=max(seg_max,0)
// makes exp(e)/(sum+EPS) equivalent within ~1e-8 rel (logits bounded ~±10).
__global__ __launch_bounds__(256) void aggregate_kernel(
    const int* __restrict__ offs,     // [N+1]
    const int* __restrict__ csr_src,  // [E]
    const float* __restrict__ esrc,   // [N][H]
    const float* __restrict__ edst,   // [N][H]
    const unsigned short* __restrict__ Whb, // [N][OUT_F*HEADS] bf16
    float* __restrict__ out)          // [N][H*OUT_F]
{
    const int wid = threadIdx.x >> 6;
    const int lane = threadIdx.x & 63;
    const int d = blockIdx.x * 4 + wid;   // 12500*4 = 50000 exact

    const int rs = offs[d];
    const int re = offs[d + 1];
    const float4 ed4 = *(const float4*)(edst + d * HEADS);

    float o0 = 0.f, o1 = 0.f, o2 = 0.f, o3 = 0.f;
    float l0 = 0.f, l1 = 0.f, l2 = 0.f, l3 = 0.f;

    for (int base = rs; base < re; base += 64) {
        const int len = re - base < 64 ? re - base : 64;
        int s = 0;
        float p0 = 0.f, p1 = 0.f, p2 = 0.f, p3 = 0.f;
        if (lane < len) {
            s = csr_src[base + lane];
            const float4 es4 = *(const float4*)(esrc + s * HEADS);
            float v0 = es4.x + ed4.x; v0 = v0 > 0.f ? v0 : NEG_SLOPE * v0;
            float v1 = es4.y + ed4.y; v1 = v1 > 0.f ? v1 : NEG_SLOPE * v1;
            float v2 = es4.z + ed4.z; v2 = v2 > 0.f ? v2 : NEG_SLOPE * v2;
            float v3 = es4.w + ed4.w; v3 = v3 > 0.f ? v3 : NEG_SLOPE * v3;
            p0 = __expf(v0); p1 = __expf(v1);
            p2 = __expf(v2); p3 = __expf(v3);
        }
        l0 += p0; l1 += p1; l2 += p2; l3 += p3;

        for (int i = 0; i < len; ++i) {
            const int   si = __shfl(s, i);
            const float q0 = __shfl(p0, i);
            const float q1 = __shfl(p1, i);
            const float q2 = __shfl(p2, i);
            const float q3 = __shfl(p3, i);
            const ushort4 w4 = *(const ushort4*)(Whb + (size_t)si * HF + (lane << 2));
            o0 += q0 * __uint_as_float((unsigned)w4.x << 16);
            o1 += q1 * __uint_as_float((unsigned)w4.y << 16);
            o2 += q2 * __uint_as_float((unsigned)w4.z << 16);
            o3 += q3 * __uint_as_float((unsigned)w4.w << 16);
        }
    }

#pragma unroll
    for (int m = 1; m < 64; m <<= 1) {
        l0 += __shfl_xor(l0, m);
        l1 += __shfl_xor(l1, m);
        l2 += __shfl_xor(l2, m);
        l3 += __shfl_xor(l3, m);
    }
    const float r0 = 1.f / (l0 + EPS);
    const float r1 = 1.f / (l1 + EPS);
    const float r2 = 1.f / (l2 + EPS);
    const float r3 = 1.f / (l3 + EPS);

    float* op = out + (size_t)d * HF + lane;
    op[0]   = o0 * r0;
    op[64]  = o1 * r1;
    op[128] = o2 * r2;
    op[192] = o3 * r3;
}

extern "C" void kernel_launch(void* const* d_in, const int* in_sizes, int n_in,
                              void* d_out, int out_size, void* d_ws, size_t ws_size,
                              hipStream_t stream) {
    const float* x      = (const float*)d_in[0];
    const int*   eidx   = (const int*)d_in[1];     // [2][E]
    const float* W      = (const float*)d_in[2];
    const float* a_src  = (const float*)d_in[3];
    const float* a_dst  = (const float*)d_in[4];
    float* out = (float*)d_out;

    const int* src = eidx;
    const int* dst = eidx + E_EDGES;

    // workspace layout
    unsigned short* Whb = (unsigned short*)d_ws;                  // N*HF bf16 (25.6 MB)
    float* esrc   = (float*)(Whb + (size_t)N_NODES * HF);         // N*H
    float* edst   = esrc + (size_t)N_NODES * HEADS;               // N*H
    int*   cursor = (int*)(edst + (size_t)N_NODES * HEADS);       // N
    int*   offs   = cursor + N_NODES;                             // N+1
    int*   bsum   = offs + N_NODES + 1;                           // 256
    int*   csr_src= bsum + 256;                                   // E
    short* Wtb    = (short*)(csr_src + E_EDGES);                  // H*OUT_F*IN_F bf16

    hipMemsetAsync(cursor, 0, (size_t)N_NODES * sizeof(int), stream);

    wcvt_kernel<<<(HEADS * IN_F * OUT_F) / 256, 256, 0, stream>>>(W, Wtb);

    proj_kernel<<<N_NODES / 16, 256, 0, stream>>>(x, Wtb, a_src, a_dst, dst,
                                                  Whb, esrc, edst, cursor);

    scan1_kernel<<<NB_SCAN, 256, 0, stream>>>(cursor, bsum);
    scan2_kernel<<<1, 256, 0, stream>>>(bsum);
    scan3_kernel<<<NB_SCAN, 256, 0, stream>>>(cursor, offs, bsum);

    const int eblocks = (E_EDGES + 255) / 256;
    scatter_kernel<<<eblocks, 256, 0, stream>>>(src, dst, cursor, csr_src);

    aggregate_kernel<<<N_NODES / 4, 256, 0, stream>>>(offs, csr_src, esrc, edst, Whb, out);
}

// Round 6
// 246.672 us; speedup vs baseline: 4.7884x; 1.0513x over previous
//
#include <hip/hip_runtime.h>
#include <hip/hip_bf16.h>

#define N_NODES 50000
#define E_EDGES 800000
#define IN_F    128
#define OUT_F   64
#define HEADS   4
#define HF      (HEADS * OUT_F)   // 256
#define NEG_SLOPE 0.2f
#define EPS     1e-8f
#define NB_SCAN ((N_NODES + 255) / 256)   // 196 scan blocks

typedef __attribute__((ext_vector_type(8))) short bf16x8;
typedef __attribute__((ext_vector_type(4))) float f32x4;

__device__ __forceinline__ unsigned short f2bf(float f) {
    return __hip_bfloat16_raw(__float2bfloat16(f)).x;
}
__device__ __forceinline__ float bf2f(unsigned short u) {
    return __uint_as_float((unsigned)u << 16);
}

// ---------------- Kernel 0: W -> bf16 transposed + cursor zeroing -----------
// grid = NB_SCAN (196) blocks x 256 = 50176 threads.
__global__ __launch_bounds__(256) void wcvt_kernel(
    const float* __restrict__ W,      // [H][IN_F][OUT_F]
    short* __restrict__ Wtb,          // [H][OUT_F][IN_F] bf16 bits
    int* __restrict__ cursor)         // [N] -> 0
{
    const int i = blockIdx.x * 256 + threadIdx.x;
    if (i < N_NODES) cursor[i] = 0;
    if (i < HEADS * IN_F * OUT_F) {
        const int h  = i >> 13;
        const int fl = (i >> 7) & 63;
        const int k  = i & 127;
        Wtb[i] = (short)f2bf(W[h * (IN_F * OUT_F) + k * OUT_F + fl]);
    }
}

// ---------------- Kernel 1: MFMA projection + logits + fused count ----------
// One block per 16 nodes (3125 blocks), 4 waves; wave w = head w.
__global__ __launch_bounds__(256) void proj_kernel(
    const float* __restrict__ x,      // [N][IN_F]
    const short* __restrict__ Wtb,    // [H][OUT_F][IN_F] bf16
    const float* __restrict__ a_src,  // [H][OUT_F]
    const float* __restrict__ a_dst,  // [H][OUT_F]
    const int* __restrict__ dst,      // [E]
    unsigned short* __restrict__ Whb, // [N][OUT_F*HEADS] bf16 ([n][f*4+h])
    float* __restrict__ esrc,         // [N][H]
    float* __restrict__ edst,         // [N][H]
    int* __restrict__ cnt)            // [N], zeroed by wcvt
{
    __shared__ short xs[16][136];            // bf16 x tile
    __shared__ unsigned short ot[16][256];   // output transpose buffer

    const int tid = threadIdx.x;
    const int n0 = blockIdx.x * 16;          // 3125 * 16 = 50000 exact

    // fused degree count: 3125 * 256 = 800000 exact
    atomicAdd(&cnt[dst[blockIdx.x * 256 + tid]], 1);

    {
        const int row = tid >> 4;
        const int kb = (tid & 15) * 8;
        const float* xp = x + (size_t)(n0 + row) * IN_F + kb;
        const float4 x0 = *(const float4*)(xp);
        const float4 x1 = *(const float4*)(xp + 4);
        bf16x8 v;
        v[0] = (short)f2bf(x0.x); v[1] = (short)f2bf(x0.y);
        v[2] = (short)f2bf(x0.z); v[3] = (short)f2bf(x0.w);
        v[4] = (short)f2bf(x1.x); v[5] = (short)f2bf(x1.y);
        v[6] = (short)f2bf(x1.z); v[7] = (short)f2bf(x1.w);
        *(bf16x8*)&xs[row][kb] = v;
    }
    __syncthreads();

    const int h = tid >> 6;
    const int lane = tid & 63;
    const int c = lane & 15;
    const int quad = lane >> 4;

    bf16x8 a[4];
#pragma unroll
    for (int ks = 0; ks < 4; ++ks)
        a[ks] = *(const bf16x8*)&xs[c][ks * 32 + quad * 8];

    f32x4 acc[4];
#pragma unroll
    for (int nt = 0; nt < 4; ++nt) acc[nt] = (f32x4){0.f, 0.f, 0.f, 0.f};

    const short* Wh_head = Wtb + (h << 13);
#pragma unroll
    for (int nt = 0; nt < 4; ++nt) {
        const short* wrow = Wh_head + ((nt * 16 + c) << 7) + (quad << 3);
#pragma unroll
        for (int ks = 0; ks < 4; ++ks) {
            const bf16x8 b = *(const bf16x8*)(wrow + (ks << 5));
            acc[nt] = __builtin_amdgcn_mfma_f32_16x16x32_bf16(a[ks], b, acc[nt], 0, 0, 0);
        }
    }

    float ps[4] = {0.f, 0.f, 0.f, 0.f};
    float pd[4] = {0.f, 0.f, 0.f, 0.f};
#pragma unroll
    for (int nt = 0; nt < 4; ++nt) {
        const float as = a_src[h * OUT_F + nt * 16 + c];
        const float ad = a_dst[h * OUT_F + nt * 16 + c];
#pragma unroll
        for (int r = 0; r < 4; ++r) {
            ps[r] += acc[nt][r] * as;
            pd[r] += acc[nt][r] * ad;
        }
    }
#pragma unroll
    for (int m = 1; m < 16; m <<= 1) {
#pragma unroll
        for (int r = 0; r < 4; ++r) {
            ps[r] += __shfl_xor(ps[r], m);
            pd[r] += __shfl_xor(pd[r], m);
        }
    }
    if (c == 0) {
#pragma unroll
        for (int r = 0; r < 4; ++r) {
            const int n = n0 + quad * 4 + r;
            esrc[n * HEADS + h] = ps[r];
            edst[n * HEADS + h] = pd[r];
        }
    }

#pragma unroll
    for (int nt = 0; nt < 4; ++nt) {
#pragma unroll
        for (int r = 0; r < 4; ++r)
            ot[quad * 4 + r][(nt * 16 + c) * 4 + h] = f2bf(acc[nt][r]);
    }
    __syncthreads();
    {
        const unsigned short* sp = &ot[0][0] + tid * 16;
        unsigned short* gp = Whb + (size_t)n0 * HF + tid * 16;
        *(int4*)(gp)     = *(const int4*)(sp);
        *(int4*)(gp + 8) = *(const int4*)(sp + 8);
    }
}

// ---------------- Scan phase 1: per-block exclusive scan --------------------
__global__ __launch_bounds__(256) void scan1_kernel(
    int* __restrict__ cursor, int* __restrict__ bsum)
{
    __shared__ int ws[4];
    const int tid = threadIdx.x;
    const int lane = tid & 63;
    const int wid = tid >> 6;
    const int i = blockIdx.x * 256 + tid;
    const int v = (i < N_NODES) ? cursor[i] : 0;
    int xv = v;
#pragma unroll
    for (int off = 1; off < 64; off <<= 1) {
        int y = __shfl_up(xv, off);
        if (lane >= off) xv += y;
    }
    if (lane == 63) ws[wid] = xv;
    __syncthreads();
    int wo = 0;
    if (wid > 0) wo += ws[0];
    if (wid > 1) wo += ws[1];
    if (wid > 2) wo += ws[2];
    const int excl = xv - v + wo;
    if (i < N_NODES) cursor[i] = excl;
    if (tid == 255) bsum[blockIdx.x] = excl + v;
}

// ---------------- Scan phase 2+3 merged: add global prefix ------------------
// Each block redundantly reduces bsum[0..blockIdx.x) (NB_SCAN=196 <= 256).
__global__ __launch_bounds__(256) void scan23_kernel(
    int* __restrict__ cursor, int* __restrict__ offs,
    const int* __restrict__ bsum)
{
    __shared__ int wsum[4];
    const int t = threadIdx.x;
    int v = (t < blockIdx.x) ? bsum[t] : 0;   // blockIdx.x <= 195 < NB_SCAN
#pragma unroll
    for (int m = 1; m < 64; m <<= 1) v += __shfl_xor(v, m);
    if ((t & 63) == 0) wsum[t >> 6] = v;
    __syncthreads();
    const int pref = wsum[0] + wsum[1] + wsum[2] + wsum[3];
    const int i = blockIdx.x * 256 + t;
    if (i < N_NODES) {
        const int val = cursor[i] + pref;
        cursor[i] = val;
        offs[i] = val;
    }
    if (i == 0) offs[N_NODES] = E_EDGES;
}

// ---------------- Kernel 2: CSR scatter -------------------------------------
__global__ __launch_bounds__(256) void scatter_kernel(
    const int* __restrict__ src,
    const int* __restrict__ dst,
    int* __restrict__ cursor,         // consumed
    int* __restrict__ csr_src)        // [E] src node ids grouped by dst
{
    const int e = blockIdx.x * 256 + threadIdx.x;
    if (e >= E_EDGES) return;
    const int pos = atomicAdd(&cursor[dst[e]], 1);
    csr_src[pos] = src[e];
}

// ---------------- Kernel 3: fused softmax + aggregation ---------------------
// One wave per dst node; batch (src,p) staged in wave-private LDS, inner loop
// uses broadcast ds_reads (no bpermute), unrolled x2 for gather overlap.
__global__ __launch_bounds__(256) void aggregate_kernel(
    const int* __restrict__ offs,     // [N+1]
    const int* __restrict__ csr_src,  // [E]
    const float* __restrict__ esrc,   // [N][H]
    const float* __restrict__ edst,   // [N][H]
    const unsigned short* __restrict__ Whb, // [N][OUT_F*HEADS] bf16
    float* __restrict__ out)          // [N][H*OUT_F]
{
    __shared__ int   sb[4][64];
    __shared__ float pb[4][64][4];

    const int wid = threadIdx.x >> 6;
    const int lane = threadIdx.x & 63;
    const int d = blockIdx.x * 4 + wid;   // 12500*4 = 50000 exact

    const int rs = offs[d];
    const int re = offs[d + 1];
    const float4 ed4 = *(const float4*)(edst + d * HEADS);
    const unsigned short* wbase = Whb + (lane << 2);

    float o0 = 0.f, o1 = 0.f, o2 = 0.f, o3 = 0.f;
    float l0 = 0.f, l1 = 0.f, l2 = 0.f, l3 = 0.f;

    for (int base = rs; base < re; base += 64) {
        const int rem = re - base;
        const int cnt = rem < 64 ? rem : 64;
        if (lane < cnt) {
            const int s = csr_src[base + lane];
            const float4 es4 = *(const float4*)(esrc + s * HEADS);
            float v0 = es4.x + ed4.x; v0 = v0 > 0.f ? v0 : NEG_SLOPE * v0;
            float v1 = es4.y + ed4.y; v1 = v1 > 0.f ? v1 : NEG_SLOPE * v1;
            float v2 = es4.z + ed4.z; v2 = v2 > 0.f ? v2 : NEG_SLOPE * v2;
            float v3 = es4.w + ed4.w; v3 = v3 > 0.f ? v3 : NEG_SLOPE * v3;
            const float p0 = __expf(v0);
            const float p1 = __expf(v1);
            const float p2 = __expf(v2);
            const float p3 = __expf(v3);
            l0 += p0; l1 += p1; l2 += p2; l3 += p3;
            sb[wid][lane] = s;
            *(float4*)pb[wid][lane] = (float4){p0, p1, p2, p3};
        }
        // wave-synchronous LDS visibility (same wave wrote it)
        int i = 0;
        for (; i + 2 <= cnt; i += 2) {
            const int s0 = sb[wid][i];
            const int s1 = sb[wid][i + 1];
            const float4 q0 = *(const float4*)pb[wid][i];
            const float4 q1 = *(const float4*)pb[wid][i + 1];
            const ushort4 w0 = *(const ushort4*)(wbase + (unsigned)s0 * HF);
            const ushort4 w1 = *(const ushort4*)(wbase + (unsigned)s1 * HF);
            o0 += q0.x * bf2f(w0.x) + q1.x * bf2f(w1.x);
            o1 += q0.y * bf2f(w0.y) + q1.y * bf2f(w1.y);
            o2 += q0.z * bf2f(w0.z) + q1.z * bf2f(w1.z);
            o3 += q0.w * bf2f(w0.w) + q1.w * bf2f(w1.w);
        }
        if (i < cnt) {
            const int s0 = sb[wid][i];
            const float4 q0 = *(const float4*)pb[wid][i];
            const ushort4 w0 = *(const ushort4*)(wbase + (unsigned)s0 * HF);
            o0 += q0.x * bf2f(w0.x);
            o1 += q0.y * bf2f(w0.y);
            o2 += q0.z * bf2f(w0.z);
            o3 += q0.w * bf2f(w0.w);
        }
    }

#pragma unroll
    for (int m = 1; m < 64; m <<= 1) {
        l0 += __shfl_xor(l0, m);
        l1 += __shfl_xor(l1, m);
        l2 += __shfl_xor(l2, m);
        l3 += __shfl_xor(l3, m);
    }
    const float r0 = 1.f / (l0 + EPS);
    const float r1 = 1.f / (l1 + EPS);
    const float r2 = 1.f / (l2 + EPS);
    const float r3 = 1.f / (l3 + EPS);

    float* op = out + (size_t)d * HF + lane;
    op[0]   = o0 * r0;
    op[64]  = o1 * r1;
    op[128] = o2 * r2;
    op[192] = o3 * r3;
}

extern "C" void kernel_launch(void* const* d_in, const int* in_sizes, int n_in,
                              void* d_out, int out_size, void* d_ws, size_t ws_size,
                              hipStream_t stream) {
    const float* x      = (const float*)d_in[0];
    const int*   eidx   = (const int*)d_in[1];     // [2][E]
    const float* W      = (const float*)d_in[2];
    const float* a_src  = (const float*)d_in[3];
    const float* a_dst  = (const float*)d_in[4];
    float* out = (float*)d_out;

    const int* src = eidx;
    const int* dst = eidx + E_EDGES;

    // workspace layout
    unsigned short* Whb = (unsigned short*)d_ws;                  // N*HF bf16 (25.6 MB)
    float* esrc   = (float*)(Whb + (size_t)N_NODES * HF);         // N*H
    float* edst   = esrc + (size_t)N_NODES * HEADS;               // N*H
    int*   cursor = (int*)(edst + (size_t)N_NODES * HEADS);       // N
    int*   offs   = cursor + N_NODES;                             // N+1
    int*   bsum   = offs + N_NODES + 1;                           // 256
    int*   csr_src= bsum + 256;                                   // E
    short* Wtb    = (short*)(csr_src + E_EDGES);                  // H*OUT_F*IN_F bf16

    wcvt_kernel<<<NB_SCAN, 256, 0, stream>>>(W, Wtb, cursor);

    proj_kernel<<<N_NODES / 16, 256, 0, stream>>>(x, Wtb, a_src, a_dst, dst,
                                                  Whb, esrc, edst, cursor);

    scan1_kernel<<<NB_SCAN, 256, 0, stream>>>(cursor, bsum);
    scan23_kernel<<<NB_SCAN, 256, 0, stream>>>(cursor, offs, bsum);

    const int eblocks = (E_EDGES + 255) / 256;
    scatter_kernel<<<eblocks, 256, 0, stream>>>(src, dst, cursor, csr_src);

    aggregate_kernel<<<N_NODES / 4, 256, 0, stream>>>(offs, csr_src, esrc, edst, Whb, out);
}